// Round 18
// baseline (53.385 us; speedup 1.0000x reference)
//
#include <hip/hip_runtime.h>
#include <math.h>

#define Bn 16
#define Nn 256
#define Mm (Nn*(Nn-1)/2)   /* 32640 */
#define CHUNK 4080         /* Mm / 8 */

typedef __attribute__((ext_vector_type(8))) _Float16 f16x8;
typedef __attribute__((ext_vector_type(4))) _Float16 f16x4;
typedef __attribute__((ext_vector_type(4))) float f32x4;
typedef __attribute__((ext_vector_type(16))) float f32x16;

typedef union { f16x8 v; _Float16 h[8]; unsigned u[4]; } H8;
typedef union { f16x4 v; _Float16 h[4]; } H4;

#define MFMA(acc, a, b) \
  acc = __builtin_amdgcn_mfma_f32_16x16x32_f16((a), (b), (acc), 0, 0, 0)
#define MFMA32(acc, a, b) \
  acc = __builtin_amdgcn_mfma_f32_32x32x16_f16((a), (b), (acc), 0, 0, 0)

__device__ __forceinline__ void top2_update(float v, int m,
    float& v1, int& i1, float& v2, int& i2)
{
  bool c1 = (v > v1) || (v == v1 && m < i1);
  bool c2 = (v > v2) || (v == v2 && m < i2);
  float nv2 = c1 ? v1 : (c2 ? v : v2);
  int   ni2 = c1 ? i1 : (c2 ? m : i2);
  v1 = c1 ? v : v1;  i1 = c1 ? m : i1;
  v2 = nv2;          i2 = ni2;
}

// permuted h-index for 32x32 C/D layout: h = (r&3)+8*(r>>2)+4*hi+32*X
// stored at px = X*32 + hi*16 + r
__device__ __forceinline__ int hperm(int h) {
  return (h >> 5) * 32 + ((h >> 2) & 1) * 16 + (h & 3) + 4 * ((h & 31) >> 3);
}

// ---------------------------------------------------------------------------
// Fused prep (128 blocks): blocks 0..63 transpose W1 -> wtg fp16 [h][k];
// blocks 64..127: obg = fp16(O); A = O@W1a + b1 (f32, h-PERMUTED for the
// 32x32 C/D layout); C = O@W1b (fp16, h-PERMUTED).
// ---------------------------------------------------------------------------
__global__ __launch_bounds__(256) void prep_all(
    const float* __restrict__ O, const float* __restrict__ W1,
    const float* __restrict__ b1,
    _Float16* __restrict__ wtg, _Float16* __restrict__ obg,
    float* __restrict__ Ag, _Float16* __restrict__ Cgh)
{
  const int t = threadIdx.x;
  if (blockIdx.x < 64) {
    const int h = blockIdx.x;
    wtg[h * 256 + t] = (_Float16)W1[t * 64 + h];
    return;
  }

  __shared__ __align__(16) _Float16 s_ob[64][72];
  __shared__ __align__(16) _Float16 s_w[64][136];   // W1a/b^T [h][k<128]
  const int l = t & 63, wv = t >> 6;
  const int lo = l & 15, g = l >> 4;
  const int bb = blockIdx.x - 64;
  const int b = bb >> 2, rt = bb & 3;
  const int r0 = rt * 64;
  const float* Ob = O + ((size_t)b * Nn + r0) * 64;

  #pragma unroll
  for (int p = 0; p < 4; ++p) {
    int v = t + p * 256;
    int r = v >> 4, c4 = (v & 15) * 4;
    float4 x = ((const float4*)Ob)[v];
    H4 pk; pk.h[0] = (_Float16)x.x; pk.h[1] = (_Float16)x.y;
           pk.h[2] = (_Float16)x.z; pk.h[3] = (_Float16)x.w;
    *(f16x4*)&s_ob[r][c4] = pk.v;
    *(f16x4*)&obg[((size_t)b * Nn + r0 + r) * 64 + c4] = pk.v;
  }
  #pragma unroll
  for (int p = 0; p < 32; ++p) {
    int kk = p * 4 + (t >> 6), h = t & 63;
    s_w[h][kk] = (_Float16)W1[kk * 64 + h];
  }
  __syncthreads();

  H8 aop[2];
  #pragma unroll
  for (int ks = 0; ks < 2; ++ks)
    aop[ks].v = *(const f16x8*)&s_ob[wv * 16 + lo][ks * 32 + g * 8];

  #pragma unroll
  for (int half = 0; half < 2; ++half) {
    #pragma unroll
    for (int nf = 0; nf < 4; ++nf) {
      f32x4 ac = {0.f, 0.f, 0.f, 0.f};
      #pragma unroll
      for (int ks = 0; ks < 2; ++ks) {
        H8 bop; bop.v = *(const f16x8*)&s_w[nf * 16 + lo][half * 64 + ks * 32 + g * 8];
        MFMA(ac, aop[ks].v, bop.v);
      }
      const int h  = nf * 16 + lo;
      const int px = hperm(h);
      if (half == 0) {
        float bbv = b1[h];
        #pragma unroll
        for (int r = 0; r < 4; ++r)
          Ag[((size_t)b * Nn + r0 + wv * 16 + g * 4 + r) * 64 + px] = ac[r] + bbv;
      } else {
        #pragma unroll
        for (int r = 0; r < 4; ++r)
          Cgh[((size_t)b * Nn + r0 + wv * 16 + g * 4 + r) * 64 + px] = (_Float16)ac[r];
      }
    }
  }
}

// ---------------------------------------------------------------------------
// Pair kernel (32x32x16 MFMA, 2 i-rows/iteration): one block = (batch,
// 16x32 tile), 4 waves. Wave owns 4 i-rows in 2 iterations; per s4-step
// 8 MFMA32 across 4 INDEPENDENT acc chains (rowA/rowB x h-lo/h-hi) so the
// matrix pipe sees 4-way chain interleave. A/C/W2 pre-permuted; Q stores
// 128B coalesced. Tripwire: WRITE_SIZE >> 2 MB = cap-forced spill.
// ---------------------------------------------------------------------------
__global__ __launch_bounds__(256, 2) void pair_kernel(
    const _Float16* __restrict__ obg,
    const float* __restrict__ Ag,
    const _Float16* __restrict__ Cgh,
    const float* __restrict__ W2,
    const float* __restrict__ b2,
    const _Float16* __restrict__ wtg,
    float* __restrict__ Q,
    float* __restrict__ cand)
{
  __shared__ __align__(16) _Float16 s_wt[64][136];  // pairwise W^T [h][k-128]
  __shared__ __align__(16) _Float16 s_oi[16][72];
  __shared__ __align__(16) float s_Ap[16][68];      // A rows, h-permuted
  __shared__ float s_w2p[64];                       // W2, h-permuted
  __shared__ float s_red[4][4];

  const int t  = threadIdx.x;
  const int l  = t & 63, wv = t >> 6;
  const int lo32 = l & 31, hi = l >> 5;

  const int blk    = blockIdx.x;
  const int within = blk >> 3;                    // 0..143
  const int batch  = (blk & 7) * 2 + within / 72; // XCD (blk%8) -> batches 2x,2x+1
  int tl           = within % 72;
  int a = 0;
  while (tl >= 8 - (a >> 1)) { tl -= 8 - (a >> 1); ++a; }
  const int c   = (a >> 1) + tl;
  const int ti0 = a * 16, tj0 = c * 32;
  const bool isdiag = (tj0 < ti0 + 16);

  const size_t obase = (size_t)batch * Nn;
  const size_t qbase = (size_t)batch * Mm;

  // ---- stage s_wt + s_oi + s_Ap + s_w2p ----
  {
    const int h = t >> 2, kq = (t & 3) * 32;
    #pragma unroll
    for (int q = 0; q < 4; ++q)
      *(f16x8*)&s_wt[h][kq + q * 8] =
          *(const f16x8*)&wtg[h * 256 + 128 + kq + q * 8];
  }
  {
    int r = t >> 4, c4 = (t & 15) * 4;
    *(f16x4*)&s_oi[r][c4] =
        *(const f16x4*)&obg[(obase + ti0 + r) * 64 + c4];
    *(f32x4*)&s_Ap[r][c4] =
        *(const f32x4*)&Ag[(obase + ti0 + r) * 64 + c4];
    if (t < 64) s_w2p[hperm(t)] = W2[t];
  }
  __syncthreads();

  // ---- hoists ----
  H8 wA[8], wB[8];
  #pragma unroll
  for (int s8 = 0; s8 < 8; ++s8) {
    wA[s8].v = *(const f16x8*)&s_wt[     lo32][s8 * 16 + hi * 8];
    wB[s8].v = *(const f16x8*)&s_wt[32 + lo32][s8 * 16 + hi * 8];
  }
  const int j = tj0 + lo32;
  H8 ojb[4];
  #pragma unroll
  for (int s4 = 0; s4 < 4; ++s4)
    ojb[s4].v = *(const f16x8*)&obg[(obase + j) * 64 + s4 * 16 + hi * 8];
  f32x4 cinA[4], cinB[4];
  #pragma unroll
  for (int q = 0; q < 4; ++q) {
    H4 ca; ca.v = *(const f16x4*)&Cgh[(obase + j) * 64 + hi * 16 + q * 4];
    H4 cb; cb.v = *(const f16x4*)&Cgh[(obase + j) * 64 + 32 + hi * 16 + q * 4];
    #pragma unroll
    for (int e = 0; e < 4; ++e) {
      cinA[q][e] = (float)ca.h[e];
      cinB[q][e] = (float)cb.h[e];
    }
  }

  const float b2v = b2[0];
  float v1 = -INFINITY, v2 = -INFINITY;
  int   i1 = 0x7fffffff, i2 = 0x7fffffff;

  // ---- main loop: 2 iterations, each covers 2 i-rows ----
  #pragma unroll
  for (int ip = 0; ip < 2; ++ip) {
    const int iLa = wv * 4 + ip * 2;
    const int iLb = iLa + 1;
    const int ia  = ti0 + iLa, ib = ti0 + iLb;

    // oi rows (broadcast)
    H8 oa[4], ob[4];
    #pragma unroll
    for (int s4 = 0; s4 < 4; ++s4) {
      oa[s4].v = *(const f16x8*)&s_oi[iLa][s4 * 16 + hi * 8];
      ob[s4].v = *(const f16x8*)&s_oi[iLb][s4 * 16 + hi * 8];
    }

    // acc init = A terms (permuted, broadcast b128)
    f32x16 accA0, accB0, accA1, accB1;
    #pragma unroll
    for (int q = 0; q < 4; ++q) {
      f32x4 av0 = *(const f32x4*)&s_Ap[iLa][hi * 16 + q * 4];
      f32x4 bv0 = *(const f32x4*)&s_Ap[iLa][32 + hi * 16 + q * 4];
      f32x4 av1 = *(const f32x4*)&s_Ap[iLb][hi * 16 + q * 4];
      f32x4 bv1 = *(const f32x4*)&s_Ap[iLb][32 + hi * 16 + q * 4];
      #pragma unroll
      for (int e = 0; e < 4; ++e) {
        accA0[q * 4 + e] = av0[e]; accB0[q * 4 + e] = bv0[e];
        accA1[q * 4 + e] = av1[e]; accB1[q * 4 + e] = bv1[e];
      }
    }

    __builtin_amdgcn_s_setprio(1);
    #pragma unroll
    for (int s4 = 0; s4 < 4; ++s4) {
      H8 fda, fpa, fdb, fpb;
      fda.v = oa[s4].v - ojb[s4].v;
      fdb.v = ob[s4].v - ojb[s4].v;
      #pragma unroll
      for (int q = 0; q < 4; ++q) {
        fda.u[q] &= 0x7FFF7FFFu;
        fdb.u[q] &= 0x7FFF7FFFu;
      }
      fpa.v = oa[s4].v * ojb[s4].v;
      fpb.v = ob[s4].v * ojb[s4].v;
      MFMA32(accA0, wA[s4].v,     fda.v);
      MFMA32(accA1, wA[s4].v,     fdb.v);
      MFMA32(accB0, wB[s4].v,     fda.v);
      MFMA32(accB1, wB[s4].v,     fdb.v);
      MFMA32(accA0, wA[s4 + 4].v, fpa.v);
      MFMA32(accA1, wA[s4 + 4].v, fpb.v);
      MFMA32(accB0, wB[s4 + 4].v, fpa.v);
      MFMA32(accB1, wB[s4 + 4].v, fpb.v);
    }
    __builtin_amdgcn_s_setprio(0);

    // epilogue: +C, relu, W2 dot, 1 shfl per row
    float pA0 = 0.f, pB0 = 0.f, pA1 = 0.f, pB1 = 0.f;
    #pragma unroll
    for (int q = 0; q < 4; ++q) {
      f32x4 wa = *(const f32x4*)&s_w2p[hi * 16 + q * 4];
      f32x4 wb = *(const f32x4*)&s_w2p[32 + hi * 16 + q * 4];
      #pragma unroll
      for (int e = 0; e < 4; ++e) {
        pA0 = fmaf(fmaxf(accA0[q * 4 + e] + cinA[q][e], 0.f), wa[e], pA0);
        pB0 = fmaf(fmaxf(accB0[q * 4 + e] + cinB[q][e], 0.f), wb[e], pB0);
        pA1 = fmaf(fmaxf(accA1[q * 4 + e] + cinA[q][e], 0.f), wa[e], pA1);
        pB1 = fmaf(fmaxf(accB1[q * 4 + e] + cinB[q][e], 0.f), wb[e], pB1);
      }
    }
    float part0 = pA0 + pB0;
    float part1 = pA1 + pB1;
    part0 += __shfl_xor(part0, 32);
    part1 += __shfl_xor(part1, 32);

    if (l < 32) {
      if (!isdiag || j > ia) {
        const int mb = ia * (Nn - 1) - (ia * (ia - 1)) / 2 - ia - 1;
        const float qv = part0 + b2v;
        Q[qbase + mb + j] = qv;
        top2_update(qv, mb + j, v1, i1, v2, i2);
      }
      if (!isdiag || j > ib) {
        const int mb = ib * (Nn - 1) - (ib * (ib - 1)) / 2 - ib - 1;
        const float qv = part1 + b2v;
        Q[qbase + mb + j] = qv;
        top2_update(qv, mb + j, v1, i1, v2, i2);
      }
    }
  }

  // ---- wave + block top-2 reduce -> cand ----
  #pragma unroll
  for (int s = 1; s < 64; s <<= 1) {
    float u1 = __shfl_xor(v1, s); int j1 = __shfl_xor(i1, s);
    float u2 = __shfl_xor(v2, s); int j2 = __shfl_xor(i2, s);
    top2_update(u1, j1, v1, i1, v2, i2);
    top2_update(u2, j2, v1, i1, v2, i2);
  }
  if (l == 0) {
    s_red[wv][0] = v1; s_red[wv][1] = __int_as_float(i1);
    s_red[wv][2] = v2; s_red[wv][3] = __int_as_float(i2);
  }
  __syncthreads();
  if (t == 0) {
    float a1 = s_red[0][0]; int x1 = __float_as_int(s_red[0][1]);
    float a2 = s_red[0][2]; int x2 = __float_as_int(s_red[0][3]);
    #pragma unroll
    for (int e = 1; e < 4; ++e) {
      top2_update(s_red[e][0], __float_as_int(s_red[e][1]), a1, x1, a2, x2);
      top2_update(s_red[e][2], __float_as_int(s_red[e][3]), a1, x1, a2, x2);
    }
    float* cp = cand + ((size_t)batch * 72 + within % 72) * 4;
    cp[0] = a1; cp[1] = __int_as_float(x1);
    cp[2] = a2; cp[3] = __int_as_float(x2);
  }
}

// ---------------------------------------------------------------------------
// Rank+mask kernel: grid (B x 8). Merges 144 candidates -> top-8,
// recomputes those 8 exactly in fp32 (wave-per-candidate, h-per-lane),
// picks exact top-2 (jax tie rule), writes mask slice.
// ---------------------------------------------------------------------------
__global__ __launch_bounds__(256) void rankmask_kernel(
    const float* __restrict__ O, const float* __restrict__ W1,
    const float* __restrict__ b1, const float* __restrict__ W2,
    const float* __restrict__ cand, float* __restrict__ mask)
{
  const int b   = blockIdx.x >> 3;
  const int cch = blockIdx.x & 7;
  const int t   = threadIdx.x;
  const int wv  = t >> 6, h = t & 63;
  __shared__ float s_cv[144];
  __shared__ int   s_ci[144];
  __shared__ int   s_m[8];
  __shared__ int   s_ij[8][2];
  __shared__ float s_or[8][2][64];
  __shared__ float s_qe[8];
  __shared__ int   s_k0, s_k1;

  if (t < 144) {
    const float* cp = cand + (size_t)(b * 72 + (t >> 1)) * 4;
    s_cv[t] = cp[(t & 1) * 2];
    s_ci[t] = __float_as_int(cp[(t & 1) * 2 + 1]);
  }
  __syncthreads();
  if (t < 144) {
    float v = s_cv[t]; int m = s_ci[t];
    int rank = 0;
    for (int e = 0; e < 144; ++e) {
      float u = s_cv[e]; int n = s_ci[e];
      rank += (u > v || (u == v && n < m)) ? 1 : 0;
    }
    if (rank < 8) s_m[rank] = m;
  }
  __syncthreads();
  if (t < 16) {
    int m = s_m[t >> 1];
    int i = 0, rem = m;
    while (rem >= Nn - 1 - i) { rem -= Nn - 1 - i; ++i; }
    int j = i + 1 + rem;
    s_ij[t >> 1][t & 1] = (t & 1) ? j : i;
  }
  __syncthreads();
  {
    int cc = t >> 5, rr = (t >> 4) & 1, c4 = (t & 15) * 4;
    int row = s_ij[cc][rr];
    *(float4*)&s_or[cc][rr][c4] = *(const float4*)&O[((size_t)b * Nn + row) * 64 + c4];
  }
  __syncthreads();
  #pragma unroll
  for (int p = 0; p < 2; ++p) {
    const int cc = p * 4 + wv;
    float z = b1[h];
    #pragma unroll 8
    for (int d = 0; d < 64; ++d) {
      float oi = s_or[cc][0][d], oj = s_or[cc][1][d];
      float f3 = fabsf(oi - oj), f4 = oi * oj;
      z += oi * W1[d * 64 + h] + oj * W1[(64 + d) * 64 + h]
         + f3 * W1[(128 + d) * 64 + h] + f4 * W1[(192 + d) * 64 + h];
    }
    float part = fmaxf(z, 0.f) * W2[h];
    #pragma unroll
    for (int s = 1; s < 64; s <<= 1) part += __shfl_xor(part, s);
    if (h == 0) s_qe[cc] = part;
  }
  __syncthreads();
  if (t == 0) {
    float v1 = -INFINITY, v2 = -INFINITY;
    int   i1 = 0x7fffffff, i2 = 0x7fffffff;
    for (int e = 0; e < 8; ++e)
      top2_update(s_qe[e], s_m[e], v1, i1, v2, i2);
    s_k0 = i1; s_k1 = i2;
  }
  __syncthreads();

  const int k0 = s_k0, k1 = s_k1;
  float* mb = mask + (size_t)b * Mm;
  const int m0 = cch * CHUNK;
  for (int m = m0 + t; m < m0 + CHUNK; m += 256)
    mb[m] = (m == k0 || m == k1) ? 1.0f : 0.0f;
}

extern "C" void kernel_launch(void* const* d_in, const int* in_sizes, int n_in,
                              void* d_out, int out_size, void* d_ws, size_t ws_size,
                              hipStream_t stream) {
  const float* O  = (const float*)d_in[0];
  const float* W1 = (const float*)d_in[1];
  const float* b1 = (const float*)d_in[2];
  const float* W2 = (const float*)d_in[3];
  const float* b2 = (const float*)d_in[4];

  float* Q    = (float*)d_out;
  float* mask = Q + (size_t)Bn * Mm;

  char* ws = (char*)d_ws;
  _Float16* wtg = (_Float16*)ws;                               // 32768 B
  _Float16* obg = (_Float16*)(ws + 32768);                     // 524288 B
  float*    Ag  = (float*)(ws + 32768 + 524288);               // 1048576 B
  _Float16* Cgh = (_Float16*)(ws + 32768 + 524288 + 1048576);  // 524288 B
  float*    cand = (float*)(ws + 32768 + 524288 + 1048576 + 524288); // 18432 B

  prep_all<<<dim3(128), dim3(256), 0, stream>>>(O, W1, b1, wtg, obg, Ag, Cgh);
  pair_kernel<<<dim3(Bn * 72), dim3(256), 0, stream>>>(obg, Ag, Cgh, W2, b2, wtg, Q, cand);
  rankmask_kernel<<<dim3(Bn * 8), dim3(256), 0, stream>>>(O, W1, b1, W2, cand, mask);
}